// Round 6
// baseline (364.081 us; speedup 1.0000x reference)
//
#include <hip/hip_runtime.h>
#include <hip/hip_bf16.h>

typedef __attribute__((ext_vector_type(8))) short s16x8;
typedef __attribute__((ext_vector_type(4))) float f32x4;

#define MFMA_B16(a, b, c) __builtin_amdgcn_mfma_f32_16x16x32_bf16((a), (b), (c), 0, 0, 0)

static __device__ __forceinline__ short f2bf(float f) {
    __hip_bfloat16 h = __float2bfloat16(f);
    return __builtin_bit_cast(short, h);
}
static __device__ __forceinline__ float rcp_f(float x) {
    return __builtin_amdgcn_rcpf(x);
}

// ---------------- fallback path (identical to R10 / 330us-measured) ----------------
__global__ void xcvt_kernel(const float* __restrict__ X, short* __restrict__ Xb, int n) {
    int i = (blockIdx.x * 256 + threadIdx.x) * 4;
    if (i < n) {
        float4 v = *(const float4*)(X + i);
        short4 o;
        o.x = f2bf(v.x); o.y = f2bf(v.y); o.z = f2bf(v.z); o.w = f2bf(v.w);
        *(short4*)(Xb + i) = o;
    }
}

// Ensemble LSTM, batch-split-8: WG = (series n, 4 batches). 256 WGs = 256 CUs.
// R15 = single-launch fusion. Evidence: bench dur_us exceeds the rocprof clstm
// dispatch by 20-32us EVERY round (R1: 362 vs 330; R5: 361 vs 341) = xcvt launch +
// inter-kernel bubble (~9% of wall). X-bf16 per WG is 128KB; LDS is 160KB and we
// use 16KB -> convert X per-WG into LDS in a prologue (~3-4us, L2-shared across the
// 32 same-bgrp WGs) and make loadx a ds_read. Loop body loses ALL VMEM (barrier
// vmcnt drain free). h-layout reverted to proven R4 4KB-padded form (330us; R14's
// compact form was +11us).
// Journal:
//   R5/R6 x-pair packing     -> +15 us (lengthened C-operand serial chain)
//   R7 lgkm-only asm barrier -> +21 us (defeated compiler scheduling)
//   R8 LDS atomicAdd pred    -> +834 us (not fire-and-forget)
//   R10 acc ping-pong + early vmem issue -> neutral (window already covered)
//   R11 exec-masked compact LDS + 2+2 chains -> +105 us (conflicts -89% but off path)
//   R12 bounds(512,4) grid 512 -> +3200 us (VGPR cap -> full weight spill)
//   R13 grid 512 bounds(512,2) -> 2x (no co-residency; chain is batch-invariant)
//   R14 compact broadcast h-buffer -> +11 us (conflicts -89% again; off critical path.
//        LDS traffic/conflicts are HIDDEN under the 795cy/SIMD MAI issue.)
__global__ __launch_bounds__(512, 2)
void clstm_fused(const float* __restrict__ X,
                 const float* __restrict__ W_ih,
                 const float* __restrict__ W_hh,
                 const float* __restrict__ b_ih,
                 const float* __restrict__ b_hh,
                 const float* __restrict__ W_out,
                 const float* __restrict__ b_out,
                 float* __restrict__ out)
{
    constexpr int B = 32, T = 512, N = 32, H = 128, G = 512;  // G = 4H
    constexpr int HT_OFF = B * T * N;
    constexpr int CT_OFF = HT_OFF + N * B * H;
    constexpr int PRED_OFF = 8192;    // pred stage: 8KB
    constexpr int XOFF = 16384;       // X bf16 slice: 128KB
    constexpr float C1 = 1.4426950408889634f;   // log2(e)

    extern __shared__ __align__(16) unsigned char smem[];  // 147456 B dynamic

    const int tid  = threadIdx.x;
    const int w    = tid >> 6;   // wave 0..7
    const int L    = tid & 63;
    const int col  = L & 15;
    const int quad = L >> 4;
    const int n    = blockIdx.x & 31;   // series
    const int bgrp = blockIdx.x >> 5;   // batch group (4 batches)

    // ---- loop-invariant weight fragments (fp32 -> bf16, once) ----
    s16x8 Bh[4][4];  // [gate tt][kt]
    s16x8 Bx[4];     // [gate tt]  k = input p 0..31
    f32x4 biasv[4];  // persistent MFMA C operand (bias broadcast)
#pragma unroll
    for (int tt = 0; tt < 4; ++tt) {
        const int g = (w + 8 * tt) * 16 + col;
        const float* whr = W_hh + ((size_t)n * G + g) * H + quad * 8;
#pragma unroll
        for (int kt = 0; kt < 4; ++kt) {
            const float* p = whr + kt * 32;
#pragma unroll
            for (int jj = 0; jj < 8; ++jj) Bh[tt][kt][jj] = f2bf(p[jj]);
        }
        const float* wir = W_ih + ((size_t)n * G + g) * N + quad * 8;
#pragma unroll
        for (int jj = 0; jj < 8; ++jj) Bx[tt][jj] = f2bf(wir[jj]);
        const float bb = b_ih[n * G + g] + b_hh[n * G + g];
        biasv[tt] = (f32x4){bb, bb, bb, bb};
    }

    // ---- pred tile: B col 0 = W_out, rotated across waves ----
    s16x8 Bp[4];
    const float bo = b_out[n];
    const f32x4 bov = (f32x4){bo, bo, bo, bo};
#pragma unroll
    for (int kt = 0; kt < 4; ++kt) {
        const float* wp = W_out + n * H + kt * 32 + quad * 8;
#pragma unroll
        for (int jj = 0; jj < 8; ++jj)
            Bp[kt][jj] = (col == 0) ? f2bf(wp[jj]) : (short)0;
    }

    // ---- h writer offset: cell (batch=quad -> m=4*quad, j=w*16+col) ----
    int wboff;
    {
        const int j = w * 16 + col;
        wboff = (j >> 5) * 1024 + (((((j >> 3) & 3) << 4) | (quad << 2)) * 16) + (j & 7) * 2;
    }

    // ---- x: lanes with col%4==0 carry batch b=col>>2 at row m=col; source = LDS ----
    const bool xactive = (col & 3) == 0;
    const int  xlbase  = XOFF + ((col >> 2) << 6) + (quad << 4);

    auto loadx = [&](int t) -> s16x8 {
        s16x8 r = (s16x8)(short)0;
        if (xactive)
            r = *(const s16x8*)(smem + xlbase + t * 256);
        return r;
    };

    // ---- prologue: zero h dbuf + pred stage; convert X slice fp32->bf16 into LDS ----
    *(float4*)(smem + tid * 16)        = make_float4(0.f, 0.f, 0.f, 0.f);  // h bufs 0..8KB
    *(float4*)(smem + 8192 + tid * 16) = make_float4(0.f, 0.f, 0.f, 0.f);  // pred 8..16KB
    {
        // xlds[t][bl][p] bf16 at XOFF + t*256 + bl*64 + p*2
        const int bgrp4 = bgrp * 4;
#pragma unroll 8
        for (int k = 0; k < 32; ++k) {
            const int e4 = (tid + (k << 9)) << 2;   // 4-float group index*4
            const int p4 = e4 & 31;
            const int t  = (e4 >> 5) & 511;
            const int bl = e4 >> 14;
            const float4 v = *(const float4*)(X + ((size_t)(bgrp4 + bl) * T + t) * N + p4);
            short4 o;
            o.x = f2bf(v.x); o.y = f2bf(v.y); o.z = f2bf(v.z); o.w = f2bf(v.w);
            *(short4*)(smem + XOFF + t * 256 + bl * 64 + p4 * 2) = o;
        }
    }
    __syncthreads();

    float cst = 0.f, hlast = 0.f;

    // prologue: accA = partial gates for t=0; prefetch x_1, x_2 (now LDS reads)
    f32x4 accA[4], accB[4];
    {
        s16x8 x0 = loadx(0);
#pragma unroll
        for (int tt = 0; tt < 4; ++tt)
            accA[tt] = MFMA_B16(x0, Bx[tt], biasv[tt]);
    }
    s16x8 xA = loadx(1);
    s16x8 xB = loadx(2);

// CUR holds x-partials (+bias) for TCUR on entry; gates accumulate in place.
// NXT computed fresh (x-partials for TCUR+1), issued first to fill the lgkm window.
#define STEP(P, TCUR, CUR, NXT)                                                     \
    {                                                                               \
        const unsigned char* rb = smem + (P) * 4096;                                \
        s16x8 Af[4];                                                                \
        _Pragma("unroll")                                                           \
        for (int kt = 0; kt < 4; ++kt)                                              \
            Af[kt] = *(const s16x8*)(rb + kt * 1024 + L * 16);                      \
        _Pragma("unroll")                                                           \
        for (int tt = 0; tt < 4; ++tt)                                              \
            NXT[tt] = MFMA_B16(xA, Bx[tt], biasv[tt]);                              \
        xA = xB;                                                                    \
        xB = loadx(((TCUR) + 3 < T) ? (TCUR) + 3 : T - 1);                          \
        _Pragma("unroll")                                                           \
        for (int tt = 0; tt < 4; ++tt)                                              \
            CUR[tt] = MFMA_B16(Af[0], Bh[tt][0], CUR[tt]);                          \
        _Pragma("unroll")                                                           \
        for (int kt = 1; kt < 4; ++kt) {                                            \
            _Pragma("unroll")                                                       \
            for (int tt = 0; tt < 4; ++tt)                                          \
                CUR[tt] = MFMA_B16(Af[kt], Bh[tt][kt], CUR[tt]);                    \
        }                                                                           \
        if (w == ((TCUR) & 7)) {                                                    \
            f32x4 pacc = bov;                                                       \
            _Pragma("unroll")                                                       \
            for (int kt = 0; kt < 4; ++kt)                                          \
                pacc = MFMA_B16(Af[kt], Bp[kt], pacc);                              \
            if ((TCUR) > 0 && col == 0)                                             \
                *(float*)(smem + PRED_OFF + ((quad << 9) + (TCUR) - 1) * 4) =       \
                    pacc[0];                                                        \
        }                                                                           \
        /* epilogue: fused-rcp activations (8 trans) */                             \
        {                                                                           \
            const float iv = CUR[0][0], fv = CUR[1][0];                             \
            const float gv = CUR[2][0], ov = CUR[3][0];                             \
            const float ei = exp2f(-C1 * iv);                                       \
            const float ef = exp2f(-C1 * fv);                                       \
            const float eg = exp2f(-2.0f * C1 * gv);                                \
            const float eo = exp2f(-C1 * ov);                                       \
            const float sf = rcp_f(1.0f + ef);                                      \
            const float itg = (1.0f - eg) * rcp_f((1.0f + ei) * (1.0f + eg));       \
            const float cc = __builtin_fmaf(sf, cst, itg);                          \
            cst = cc;                                                               \
            const float ec = exp2f(-2.0f * C1 * cc);                                \
            const float hv = (1.0f - ec) * rcp_f((1.0f + eo) * (1.0f + ec));        \
            hlast = hv;                                                             \
            *(short*)(smem + ((P) ^ 1) * 4096 + wboff) = f2bf(hv);                  \
        }                                                                           \
        __syncthreads();                                                            \
    }

#pragma unroll 1
    for (int t2 = 0; t2 < T; t2 += 2) {
        STEP(0, t2, accA, accB)
        STEP(1, t2 + 1, accB, accA)
    }
#undef STEP

    // ---- tail pred: t = T-1 uses h_{T-1}, sitting in buffer 0 ----
    if (w == 0) {
        f32x4 pacc = bov;
#pragma unroll
        for (int kt = 0; kt < 4; ++kt) {
            s16x8 Af = *(const s16x8*)(smem + kt * 1024 + L * 16);
            pacc = MFMA_B16(Af, Bp[kt], pacc);
        }
        if (col == 0)
            *(float*)(smem + PRED_OFF + ((quad << 9) + (T - 1)) * 4) = pacc[0];
    }
    __syncthreads();

    // ---- flush pred stage -> global ----
#pragma unroll
    for (int e = tid; e < 4 * T; e += 512) {
        const int b = e >> 9, t = e & (T - 1);
        out[((size_t)(bgrp * 4 + b) * T + t) * N + n] =
            *(const float*)(smem + PRED_OFF + e * 4);
    }

    // ---- final hT, cT ----
    {
        const int bglob = bgrp * 4 + quad;
        const int j = w * 16 + col;
        out[HT_OFF + ((size_t)n * B + bglob) * H + j] = hlast;
        out[CT_OFF + ((size_t)n * B + bglob) * H + j] = cst;
    }
}

// ---------------- fallback kernel (R10 structure, static 16KB LDS) ----------------
template<bool BF16X>
__global__ __launch_bounds__(512, 2)
void clstm_kernel(const float* __restrict__ X,
                  const short* __restrict__ Xb,
                  const float* __restrict__ W_ih,
                  const float* __restrict__ W_hh,
                  const float* __restrict__ b_ih,
                  const float* __restrict__ b_hh,
                  const float* __restrict__ W_out,
                  const float* __restrict__ b_out,
                  float* __restrict__ out)
{
    constexpr int B = 32, T = 512, N = 32, H = 128, G = 512;
    constexpr int HT_OFF = B * T * N;
    constexpr int CT_OFF = HT_OFF + N * B * H;
    constexpr int PRED_OFF = 8192;
    constexpr float C1 = 1.4426950408889634f;

    __shared__ __align__(16) unsigned char smem[16384];

    const int tid  = threadIdx.x;
    const int w    = tid >> 6;
    const int L    = tid & 63;
    const int col  = L & 15;
    const int quad = L >> 4;
    const int n    = blockIdx.x & 31;
    const int bgrp = blockIdx.x >> 5;

    s16x8 Bh[4][4];
    s16x8 Bx[4];
    f32x4 biasv[4];
#pragma unroll
    for (int tt = 0; tt < 4; ++tt) {
        const int g = (w + 8 * tt) * 16 + col;
        const float* whr = W_hh + ((size_t)n * G + g) * H + quad * 8;
#pragma unroll
        for (int kt = 0; kt < 4; ++kt) {
            const float* p = whr + kt * 32;
#pragma unroll
            for (int jj = 0; jj < 8; ++jj) Bh[tt][kt][jj] = f2bf(p[jj]);
        }
        const float* wir = W_ih + ((size_t)n * G + g) * N + quad * 8;
#pragma unroll
        for (int jj = 0; jj < 8; ++jj) Bx[tt][jj] = f2bf(wir[jj]);
        const float bb = b_ih[n * G + g] + b_hh[n * G + g];
        biasv[tt] = (f32x4){bb, bb, bb, bb};
    }

    s16x8 Bp[4];
    const float bo = b_out[n];
    const f32x4 bov = (f32x4){bo, bo, bo, bo};
#pragma unroll
    for (int kt = 0; kt < 4; ++kt) {
        const float* wp = W_out + n * H + kt * 32 + quad * 8;
#pragma unroll
        for (int jj = 0; jj < 8; ++jj)
            Bp[kt][jj] = (col == 0) ? f2bf(wp[jj]) : (short)0;
    }

    int wboff;
    {
        const int j = w * 16 + col;
        wboff = (j >> 5) * 1024 + (((((j >> 3) & 3) << 4) | (quad << 2)) * 16) + (j & 7) * 2;
    }

    const bool xactive = (col & 3) == 0;
    const int  xb      = bgrp * 4 + (col >> 2);
    const float* xp  = X + ((size_t)xb * T) * N + quad * 8;
    const short* xbp = BF16X ? (Xb + ((size_t)xb * T) * N + quad * 8) : nullptr;

    auto loadx = [&](int t) -> s16x8 {
        s16x8 r = (s16x8)(short)0;
        if (xactive) {
            if constexpr (BF16X) {
                r = *(const s16x8*)(xbp + (size_t)t * N);
            } else {
                float4 lo = *(const float4*)(xp + (size_t)t * N);
                float4 hi = *(const float4*)(xp + (size_t)t * N + 4);
                r[0] = f2bf(lo.x); r[1] = f2bf(lo.y); r[2] = f2bf(lo.z); r[3] = f2bf(lo.w);
                r[4] = f2bf(hi.x); r[5] = f2bf(hi.y); r[6] = f2bf(hi.z); r[7] = f2bf(hi.w);
            }
        }
        return r;
    };

    *(float4*)(smem + tid * 16)        = make_float4(0.f, 0.f, 0.f, 0.f);
    *(float4*)(smem + 8192 + tid * 16) = make_float4(0.f, 0.f, 0.f, 0.f);

    float cst = 0.f, hlast = 0.f;

    f32x4 accA[4], accB[4];
    {
        s16x8 x0 = loadx(0);
#pragma unroll
        for (int tt = 0; tt < 4; ++tt)
            accA[tt] = MFMA_B16(x0, Bx[tt], biasv[tt]);
    }
    s16x8 xA = loadx(1);
    s16x8 xB = loadx(2);

    __syncthreads();

#define STEP(P, TCUR, CUR, NXT)                                                     \
    {                                                                               \
        const unsigned char* rb = smem + (P) * 4096;                                \
        s16x8 Af[4];                                                                \
        _Pragma("unroll")                                                           \
        for (int kt = 0; kt < 4; ++kt)                                              \
            Af[kt] = *(const s16x8*)(rb + kt * 1024 + L * 16);                      \
        _Pragma("unroll")                                                           \
        for (int tt = 0; tt < 4; ++tt)                                              \
            NXT[tt] = MFMA_B16(xA, Bx[tt], biasv[tt]);                              \
        xA = xB;                                                                    \
        xB = loadx(((TCUR) + 3 < T) ? (TCUR) + 3 : T - 1);                          \
        _Pragma("unroll")                                                           \
        for (int tt = 0; tt < 4; ++tt)                                              \
            CUR[tt] = MFMA_B16(Af[0], Bh[tt][0], CUR[tt]);                          \
        _Pragma("unroll")                                                           \
        for (int kt = 1; kt < 4; ++kt) {                                            \
            _Pragma("unroll")                                                       \
            for (int tt = 0; tt < 4; ++tt)                                          \
                CUR[tt] = MFMA_B16(Af[kt], Bh[tt][kt], CUR[tt]);                    \
        }                                                                           \
        if (w == ((TCUR) & 7)) {                                                    \
            f32x4 pacc = bov;                                                       \
            _Pragma("unroll")                                                       \
            for (int kt = 0; kt < 4; ++kt)                                          \
                pacc = MFMA_B16(Af[kt], Bp[kt], pacc);                              \
            if ((TCUR) > 0 && col == 0)                                             \
                *(float*)(smem + PRED_OFF + ((quad << 9) + (TCUR) - 1) * 4) =       \
                    pacc[0];                                                        \
        }                                                                           \
        {                                                                           \
            const float iv = CUR[0][0], fv = CUR[1][0];                             \
            const float gv = CUR[2][0], ov = CUR[3][0];                             \
            const float ei = exp2f(-C1 * iv);                                       \
            const float ef = exp2f(-C1 * fv);                                       \
            const float eg = exp2f(-2.0f * C1 * gv);                                \
            const float eo = exp2f(-C1 * ov);                                       \
            const float sf = rcp_f(1.0f + ef);                                      \
            const float itg = (1.0f - eg) * rcp_f((1.0f + ei) * (1.0f + eg));       \
            const float cc = __builtin_fmaf(sf, cst, itg);                          \
            cst = cc;                                                               \
            const float ec = exp2f(-2.0f * C1 * cc);                                \
            const float hv = (1.0f - ec) * rcp_f((1.0f + eo) * (1.0f + ec));        \
            hlast = hv;                                                             \
            *(short*)(smem + ((P) ^ 1) * 4096 + wboff) = f2bf(hv);                  \
        }                                                                           \
        __syncthreads();                                                            \
    }

#pragma unroll 1
    for (int t2 = 0; t2 < T; t2 += 2) {
        STEP(0, t2, accA, accB)
        STEP(1, t2 + 1, accB, accA)
    }
#undef STEP

    if (w == 0) {
        f32x4 pacc = bov;
#pragma unroll
        for (int kt = 0; kt < 4; ++kt) {
            s16x8 Af = *(const s16x8*)(smem + kt * 1024 + L * 16);
            pacc = MFMA_B16(Af, Bp[kt], pacc);
        }
        if (col == 0)
            *(float*)(smem + PRED_OFF + ((quad << 9) + (T - 1)) * 4) = pacc[0];
    }
    __syncthreads();

#pragma unroll
    for (int e = tid; e < 4 * T; e += 512) {
        const int b = e >> 9, t = e & (T - 1);
        out[((size_t)(bgrp * 4 + b) * T + t) * N + n] =
            *(const float*)(smem + PRED_OFF + e * 4);
    }

    {
        const int bglob = bgrp * 4 + quad;
        const int j = w * 16 + col;
        out[HT_OFF + ((size_t)n * B + bglob) * H + j] = hlast;
        out[CT_OFF + ((size_t)n * B + bglob) * H + j] = cst;
    }
}

extern "C" void kernel_launch(void* const* d_in, const int* in_sizes, int n_in,
                              void* d_out, int out_size, void* d_ws, size_t ws_size,
                              hipStream_t stream) {
    const float* X     = (const float*)d_in[0];
    const float* W_ih  = (const float*)d_in[1];
    const float* W_hh  = (const float*)d_in[2];
    const float* b_ih  = (const float*)d_in[3];
    const float* b_hh  = (const float*)d_in[4];
    const float* W_out = (const float*)d_in[5];
    const float* b_out = (const float*)d_in[6];
    float* out = (float*)d_out;

    constexpr int SMEM_BYTES = 16384 + 131072;  // h dbuf + pred (16KB) + X bf16 (128KB)

    static int mode = -1;
    if (mode < 0) {
        hipError_t e = hipFuncSetAttribute(
            reinterpret_cast<const void*>(&clstm_fused),
            hipFuncAttributeMaxDynamicSharedMemorySize, SMEM_BYTES);
        mode = (e == hipSuccess) ? 1 : 0;
    }

    if (mode) {
        clstm_fused<<<dim3(256), dim3(512), SMEM_BYTES, stream>>>(
            X, W_ih, W_hh, b_ih, b_hh, W_out, b_out, out);
    } else {
        const int xelems = 32 * 512 * 32;  // B*T*N
        const bool usebf = ws_size >= (size_t)xelems * sizeof(short);
        if (usebf) {
            short* Xb = (short*)d_ws;
            xcvt_kernel<<<dim3(xelems / 1024), dim3(256), 0, stream>>>(X, Xb, xelems);
            clstm_kernel<true><<<dim3(256), dim3(512), 0, stream>>>(
                X, Xb, W_ih, W_hh, b_ih, b_hh, W_out, b_out, out);
        } else {
            clstm_kernel<false><<<dim3(256), dim3(512), 0, stream>>>(
                X, nullptr, W_ih, W_hh, b_ih, b_hh, W_out, b_out, out);
        }
    }
}

// Round 7
// 355.699 us; speedup vs baseline: 1.0236x; 1.0236x over previous
//
#include <hip/hip_runtime.h>
#include <hip/hip_bf16.h>

typedef __attribute__((ext_vector_type(8))) short s16x8;
typedef __attribute__((ext_vector_type(4))) float f32x4;

#define MFMA_B16(a, b, c) __builtin_amdgcn_mfma_f32_16x16x32_bf16((a), (b), (c), 0, 0, 0)

static __device__ __forceinline__ short f2bf(float f) {
    __hip_bfloat16 h = __float2bfloat16(f);
    return __builtin_bit_cast(short, h);
}
static __device__ __forceinline__ float rcp_f(float x) {
    return __builtin_amdgcn_rcpf(x);
}

// pre-pass: X fp32 -> bf16 in workspace
__global__ void xcvt_kernel(const float* __restrict__ X, short* __restrict__ Xb, int n) {
    int i = (blockIdx.x * 256 + threadIdx.x) * 4;
    if (i < n) {
        float4 v = *(const float4*)(X + i);
        short4 o;
        o.x = f2bf(v.x); o.y = f2bf(v.y); o.z = f2bf(v.z); o.w = f2bf(v.w);
        *(short4*)(Xb + i) = o;
    }
}

// Ensemble LSTM, batch-split-8: WG = (series n, 4 batches). 256 WGs = 256 CUs.
// R16 = 4-step-grouped x-projection. Step = 1548cy, 795cy/SIMD MFMA issue
// (164 MFMA/CU/step); the 32 accN MFMAs/step have 4/16 real M-rows and, unlike the
// h-GEMM, the waste is avoidable (x known ahead). Pack A rows = 4*batch+tsub:
// 4 MFMAs per wave per 4 steps replace 16. D-layout row=(lane>>4)*4+reg puts
// acc4[tt][j] = xproj(step tg+j, batch=quad) exactly where the 1-cell/lane epilogue
// needs it. Per-step C rebuilt as splat of acc4[tt][j] (elems 1-3 feed unused rows,
// garbage-tolerant). Bit-identical gate math. MFMA/CU/step 164->140. Loop body has
// zero VMEM (1 prefetch load per 4 steps).
// Journal:
//   R5/R6 x-pair packing     -> +15 us (lengthened C-operand serial chain)
//   R7 lgkm-only asm barrier -> +21 us (defeated compiler scheduling)
//   R8 LDS atomicAdd pred    -> +834 us (not fire-and-forget)
//   R10 acc ping-pong + early vmem issue -> neutral (window already covered)
//   R11 exec-masked compact LDS + 2+2 chains -> +105 us (conflicts -89% but off path)
//   R12 bounds(512,4) grid 512 -> +3200 us (VGPR cap -> full weight spill)
//   R13 grid 512 bounds(512,2) -> 2x (no co-residency; chain is batch-invariant)
//   R14 compact broadcast h-buffer -> +11 us (conflicts off critical path)
//   R15 fused xcvt into LDS -> bench neutral (the 25-29us bench-vs-rocprof gap is
//        fixed harness overhead, not launch count). Reverted to two-kernel.
template<bool BF16X>
__global__ __launch_bounds__(512, 2)
void clstm_kernel(const float* __restrict__ X,
                  const short* __restrict__ Xb,
                  const float* __restrict__ W_ih,
                  const float* __restrict__ W_hh,
                  const float* __restrict__ b_ih,
                  const float* __restrict__ b_hh,
                  const float* __restrict__ W_out,
                  const float* __restrict__ b_out,
                  float* __restrict__ out)
{
    constexpr int B = 32, T = 512, N = 32, H = 128, G = 512;  // G = 4H
    constexpr int HT_OFF = B * T * N;
    constexpr int CT_OFF = HT_OFF + N * B * H;
    constexpr int PRED_OFF = 8192;
    constexpr float C1 = 1.4426950408889634f;   // log2(e)

    __shared__ __align__(16) unsigned char smem[16384];

    const int tid  = threadIdx.x;
    const int w    = tid >> 6;   // wave 0..7
    const int L    = tid & 63;
    const int col  = L & 15;
    const int quad = L >> 4;
    const int n    = blockIdx.x & 31;   // series
    const int bgrp = blockIdx.x >> 5;   // batch group (4 batches)

    // ---- loop-invariant weight fragments (fp32 -> bf16, once) ----
    s16x8 Bh[4][4];  // [gate tt][kt]
    s16x8 Bx[4];     // [gate tt]  k = input p 0..31
    f32x4 biasv[4];  // persistent MFMA C operand (bias broadcast)
#pragma unroll
    for (int tt = 0; tt < 4; ++tt) {
        const int g = (w + 8 * tt) * 16 + col;
        const float* whr = W_hh + ((size_t)n * G + g) * H + quad * 8;
#pragma unroll
        for (int kt = 0; kt < 4; ++kt) {
            const float* p = whr + kt * 32;
#pragma unroll
            for (int jj = 0; jj < 8; ++jj) Bh[tt][kt][jj] = f2bf(p[jj]);
        }
        const float* wir = W_ih + ((size_t)n * G + g) * N + quad * 8;
#pragma unroll
        for (int jj = 0; jj < 8; ++jj) Bx[tt][jj] = f2bf(wir[jj]);
        const float bb = b_ih[n * G + g] + b_hh[n * G + g];
        biasv[tt] = (f32x4){bb, bb, bb, bb};
    }

    // ---- pred tile: B col 0 = W_out, rotated across waves ----
    s16x8 Bp[4];
    const float bo = b_out[n];
    const f32x4 bov = (f32x4){bo, bo, bo, bo};
#pragma unroll
    for (int kt = 0; kt < 4; ++kt) {
        const float* wp = W_out + n * H + kt * 32 + quad * 8;
#pragma unroll
        for (int jj = 0; jj < 8; ++jj)
            Bp[kt][jj] = (col == 0) ? f2bf(wp[jj]) : (short)0;
    }

    // ---- h writer offset: cell (batch=quad -> m=4*quad, j=w*16+col) ----
    int wboff;
    {
        const int j = w * 16 + col;
        wboff = (j >> 5) * 1024 + (((((j >> 3) & 3) << 4) | (quad << 2)) * 16) + (j & 7) * 2;
    }

    // ---- grouped x loader: ALL lanes; A row = 4*batch + tsub ----
    // lane (quad, col): batch = col>>2, tsub = col&3, k = quad*8..+8
    const int xb = bgrp * 4 + (col >> 2);
    const int ts = col & 3;
    const float* xp  = X + ((size_t)xb * T + ts) * N + quad * 8;
    const short* xbp = BF16X ? (Xb + ((size_t)xb * T + ts) * N + quad * 8) : nullptr;

    auto loadxg = [&](int tg) -> s16x8 {
        if constexpr (BF16X) {
            return *(const s16x8*)(xbp + (size_t)tg * N);
        } else {
            float4 lo = *(const float4*)(xp + (size_t)tg * N);
            float4 hi = *(const float4*)(xp + (size_t)tg * N + 4);
            s16x8 r;
            r[0] = f2bf(lo.x); r[1] = f2bf(lo.y); r[2] = f2bf(lo.z); r[3] = f2bf(lo.w);
            r[4] = f2bf(hi.x); r[5] = f2bf(hi.y); r[6] = f2bf(hi.z); r[7] = f2bf(hi.w);
            return r;
        }
    };

    // zero frag buffers (pad rows must stay 0) + pred stage
    *(float4*)(smem + tid * 16)        = make_float4(0.f, 0.f, 0.f, 0.f);
    *(float4*)(smem + 8192 + tid * 16) = make_float4(0.f, 0.f, 0.f, 0.f);

    float cst = 0.f, hlast = 0.f;

    // prologue: x for group 0 and prefetch for group 1
    s16x8 xgC = loadxg(0);
    s16x8 xgN = loadxg(4);

    __syncthreads();

// Per step: Af from LDS; C operand = splat of acc4[tt][J] (xproj+bias for this step);
// gates accumulate in place; pred wave rotates; epilogue reads cur[tt][0].
#define STEP(P, TCUR, J)                                                            \
    {                                                                               \
        const unsigned char* rb = smem + (P) * 4096;                                \
        s16x8 Af[4];                                                                \
        _Pragma("unroll")                                                           \
        for (int kt = 0; kt < 4; ++kt)                                              \
            Af[kt] = *(const s16x8*)(rb + kt * 1024 + L * 16);                      \
        f32x4 cur[4];                                                               \
        _Pragma("unroll")                                                           \
        for (int tt = 0; tt < 4; ++tt) {                                            \
            const float a = acc4[tt][(J)];                                          \
            cur[tt] = (f32x4){a, a, a, a};                                          \
        }                                                                           \
        _Pragma("unroll")                                                           \
        for (int kt = 0; kt < 4; ++kt) {                                            \
            _Pragma("unroll")                                                       \
            for (int tt = 0; tt < 4; ++tt)                                          \
                cur[tt] = MFMA_B16(Af[kt], Bh[tt][kt], cur[tt]);                    \
        }                                                                           \
        if (w == ((TCUR) & 7)) {                                                    \
            f32x4 pacc = bov;                                                       \
            _Pragma("unroll")                                                       \
            for (int kt = 0; kt < 4; ++kt)                                          \
                pacc = MFMA_B16(Af[kt], Bp[kt], pacc);                              \
            if ((TCUR) > 0 && col == 0)                                             \
                *(float*)(smem + PRED_OFF + ((quad << 9) + (TCUR) - 1) * 4) =       \
                    pacc[0];                                                        \
        }                                                                           \
        /* epilogue: fused-rcp activations (8 trans) */                             \
        {                                                                           \
            const float iv = cur[0][0], fv = cur[1][0];                             \
            const float gv = cur[2][0], ov = cur[3][0];                             \
            const float ei = exp2f(-C1 * iv);                                       \
            const float ef = exp2f(-C1 * fv);                                       \
            const float eg = exp2f(-2.0f * C1 * gv);                                \
            const float eo = exp2f(-C1 * ov);                                       \
            const float sf = rcp_f(1.0f + ef);                                      \
            const float itg = (1.0f - eg) * rcp_f((1.0f + ei) * (1.0f + eg));       \
            const float cc = __builtin_fmaf(sf, cst, itg);                          \
            cst = cc;                                                               \
            const float ec = exp2f(-2.0f * C1 * cc);                                \
            const float hv = (1.0f - ec) * rcp_f((1.0f + eo) * (1.0f + ec));        \
            hlast = hv;                                                             \
            *(short*)(smem + ((P) ^ 1) * 4096 + wboff) = f2bf(hv);                  \
        }                                                                           \
        __syncthreads();                                                            \
    }

#pragma unroll 1
    for (int tg = 0; tg < T; tg += 4) {
        // group top: 4 MFMAs produce xproj(+bias) for steps tg..tg+3 (h-independent,
        // issues into the post-barrier lgkm window); prefetch next group's x.
        f32x4 acc4[4];
#pragma unroll
        for (int tt = 0; tt < 4; ++tt)
            acc4[tt] = MFMA_B16(xgC, Bx[tt], biasv[tt]);
        xgC = xgN;
        xgN = loadxg((tg + 8 < T) ? (tg + 8) : (T - 4));
        STEP(0, tg + 0, 0)
        STEP(1, tg + 1, 1)
        STEP(0, tg + 2, 2)
        STEP(1, tg + 3, 3)
    }
#undef STEP

    // ---- tail pred: t = T-1 uses h_{T-1}, sitting in buffer 0 ----
    if (w == 0) {
        f32x4 pacc = bov;
#pragma unroll
        for (int kt = 0; kt < 4; ++kt) {
            s16x8 Af = *(const s16x8*)(smem + kt * 1024 + L * 16);
            pacc = MFMA_B16(Af, Bp[kt], pacc);
        }
        if (col == 0)
            *(float*)(smem + PRED_OFF + ((quad << 9) + (T - 1)) * 4) = pacc[0];
    }
    __syncthreads();

    // ---- flush pred stage -> global ----
#pragma unroll
    for (int e = tid; e < 4 * T; e += 512) {
        const int b = e >> 9, t = e & (T - 1);
        out[((size_t)(bgrp * 4 + b) * T + t) * N + n] =
            *(const float*)(smem + PRED_OFF + e * 4);
    }

    // ---- final hT, cT ----
    {
        const int bglob = bgrp * 4 + quad;
        const int j = w * 16 + col;
        out[HT_OFF + ((size_t)n * B + bglob) * H + j] = hlast;
        out[CT_OFF + ((size_t)n * B + bglob) * H + j] = cst;
    }
}

extern "C" void kernel_launch(void* const* d_in, const int* in_sizes, int n_in,
                              void* d_out, int out_size, void* d_ws, size_t ws_size,
                              hipStream_t stream) {
    const float* X     = (const float*)d_in[0];
    const float* W_ih  = (const float*)d_in[1];
    const float* W_hh  = (const float*)d_in[2];
    const float* b_ih  = (const float*)d_in[3];
    const float* b_hh  = (const float*)d_in[4];
    const float* W_out = (const float*)d_in[5];
    const float* b_out = (const float*)d_in[6];
    float* out = (float*)d_out;

    const int xelems = 32 * 512 * 32;  // B*T*N
    const bool usebf = ws_size >= (size_t)xelems * sizeof(short);

    if (usebf) {
        short* Xb = (short*)d_ws;
        xcvt_kernel<<<dim3(xelems / 1024), dim3(256), 0, stream>>>(X, Xb, xelems);
        clstm_kernel<true><<<dim3(256), dim3(512), 0, stream>>>(
            X, Xb, W_ih, W_hh, b_ih, b_hh, W_out, b_out, out);
    } else {
        clstm_kernel<false><<<dim3(256), dim3(512), 0, stream>>>(
            X, nullptr, W_ih, W_hh, b_ih, b_hh, W_out, b_out, out);
    }
}